// Round 1
// baseline (164.399 us; speedup 1.0000x reference)
//
#include <hip/hip_runtime.h>
#include <hip/hip_bf16.h>
#include <cstdint>

#define HEADS 12
#define SCALE 0.125f

typedef __attribute__((ext_vector_type(8))) __bf16 bf16x8;
typedef __attribute__((ext_vector_type(4))) __bf16 bf16x4;
typedef __attribute__((ext_vector_type(4))) float f32x4;

#define AS1 __attribute__((address_space(1)))
#define AS3 __attribute__((address_space(3)))

__device__ __forceinline__ void gload16(const void* src, void* lds) {
  __builtin_amdgcn_global_load_lds((AS1 void*)src, (AS3 void*)lds, 16, 0, 0);
}

// ---------------- cast fp32 -> bf16 (flat, vectorized) ----------------
__global__ void k_cast(const float* __restrict__ in, __bf16* __restrict__ out, int n) {
  int i = (blockIdx.x * 256 + threadIdx.x) * 4;
  if (i + 3 < n) {
    float4 v = *(const float4*)(in + i);
    bf16x4 o;
    o[0] = (__bf16)v.x; o[1] = (__bf16)v.y; o[2] = (__bf16)v.z; o[3] = (__bf16)v.w;
    *(bf16x4*)(out + i) = o;
  }
}

// ------------- transpose+cast weight: W[K][N] f32 -> Wt[N][K] bf16 -------------
__global__ void k_twc(const float* __restrict__ W, __bf16* __restrict__ Wt, int K, int N) {
  __shared__ float tile[32][33];
  int nt = blockIdx.x, kt = blockIdx.y;
  int c = threadIdx.x & 31, r0 = threadIdx.x >> 5;
#pragma unroll
  for (int i = 0; i < 4; ++i) {
    int r = r0 + i * 8;
    tile[r][c] = W[(size_t)(kt * 32 + r) * N + nt * 32 + c];
  }
  __syncthreads();
#pragma unroll
  for (int i = 0; i < 4; ++i) {
    int r = r0 + i * 8;
    Wt[(size_t)(nt * 32 + r) * K + kt * 32 + c] = (__bf16)tile[c][r];
  }
}

// ------------- transpose V slice of kv into vT[b][h*64+d][m] (bf16) -------------
__global__ void k_tv(const __bf16* __restrict__ kv, __bf16* __restrict__ vT) {
  __shared__ __bf16 tile[32][33];
  int mt = blockIdx.x, ct = blockIdx.y, b = blockIdx.z;
  int c = threadIdx.x & 31, r0 = threadIdx.x >> 5;
#pragma unroll
  for (int i = 0; i < 4; ++i) {
    int r = r0 + i * 8;  // m-local
    tile[r][c] = kv[((size_t)(b * 1024 + mt * 32 + r)) * 1536 + 768 + ct * 32 + c];
  }
  __syncthreads();
#pragma unroll
  for (int i = 0; i < 4; ++i) {
    int r = r0 + i * 8;  // c-local
    vT[((size_t)(b * 768 + ct * 32 + r)) * 1024 + mt * 32 + c] = tile[c][r];
  }
}

// ---------------- bf16 GEMM: C[M][N] = A[M][K] * Bt[N][K]^T ----------------
// 128x128 tile, BK=64, 4 waves (2x2), each wave 64x64 out. LDS double-buffered.
// global_load_lds width16, XOR-swizzled (pre-swizzled global source).
template<bool BF16OUT>
__global__ __launch_bounds__(256, 2) void k_gemm(
    const __bf16* __restrict__ A, const __bf16* __restrict__ Bt,
    void* __restrict__ C, const float* __restrict__ bias, int M, int N, int K) {
  __shared__ __align__(16) char ldsA[2][16384];
  __shared__ __align__(16) char ldsB[2][16384];
  const int tid = threadIdx.x;
  const int ln = tid & 63;
  const int w = tid >> 6;
  const int bm0 = blockIdx.y * 128, bn0 = blockIdx.x * 128;
  const int wm0 = (w >> 1) * 64, wn0 = (w & 1) * 64;

  auto stage = [&](char* lds, const __bf16* G, int row0, int k0) {
    const char* gb = (const char*)(G + (size_t)row0 * K + k0);
#pragma unroll
    for (int c = 0; c < 4; ++c) {
      int off = c * 4096 + tid * 16;
      int row = off >> 7;
      int s = ((off >> 4) & 7) ^ (row & 7);
      gload16(gb + (size_t)row * (K * 2) + (s << 4), lds + c * 4096 + (w << 10));
    }
  };

  f32x4 acc[4][4] = {};
  const int NK = K >> 6;
  stage(ldsA[0], A, bm0, 0);
  stage(ldsB[0], Bt, bn0, 0);
  __syncthreads();
  for (int kt = 0; kt < NK; ++kt) {
    const char* bufA = ldsA[kt & 1];
    const char* bufB = ldsB[kt & 1];
    if (kt + 1 < NK) {
      stage(ldsA[(kt + 1) & 1], A, bm0, (kt + 1) << 6);
      stage(ldsB[(kt + 1) & 1], Bt, bn0, (kt + 1) << 6);
    }
    bf16x8 af[2][4], bf[2][4];
#pragma unroll
    for (int kk = 0; kk < 2; ++kk)
#pragma unroll
      for (int mt = 0; mt < 4; ++mt) {
        int row = wm0 + mt * 16 + (ln & 15);
        af[kk][mt] = *(const bf16x8*)(bufA + row * 128 + (((kk * 4 + (ln >> 4)) ^ (row & 7)) << 4));
      }
#pragma unroll
    for (int kk = 0; kk < 2; ++kk)
#pragma unroll
      for (int nt = 0; nt < 4; ++nt) {
        int row = wn0 + nt * 16 + (ln & 15);
        bf[kk][nt] = *(const bf16x8*)(bufB + row * 128 + (((kk * 4 + (ln >> 4)) ^ (row & 7)) << 4));
      }
#pragma unroll
    for (int kk = 0; kk < 2; ++kk)
#pragma unroll
      for (int mt = 0; mt < 4; ++mt)
#pragma unroll
        for (int nt = 0; nt < 4; ++nt)
          acc[mt][nt] = __builtin_amdgcn_mfma_f32_16x16x32_bf16(af[kk][mt], bf[kk][nt], acc[mt][nt], 0, 0, 0);
    __syncthreads();
  }
#pragma unroll
  for (int mt = 0; mt < 4; ++mt) {
    int row = bm0 + wm0 + mt * 16 + ((ln >> 4) << 2);
#pragma unroll
    for (int nt = 0; nt < 4; ++nt) {
      int col = bn0 + wn0 + nt * 16 + (ln & 15);
      if (BF16OUT) {
        __bf16* Cb = (__bf16*)C;
#pragma unroll
        for (int jj = 0; jj < 4; ++jj)
          Cb[(size_t)(row + jj) * N + col] = (__bf16)acc[mt][nt][jj];
      } else {
        float* Cf = (float*)C;
        float bv = bias[col];
#pragma unroll
        for (int jj = 0; jj < 4; ++jj)
          Cf[(size_t)(row + jj) * N + col] = acc[mt][nt][jj] + bv;
      }
    }
  }
}

// ---------------- flash attention: q(8192x768), kv(4096x1536), vT(b,768,1024) ----------------
// block = (qtile of 64 rows, b*h). 4 waves x 16 q rows. KVBLK=64, 16 iters.
__global__ void k_attn(const __bf16* __restrict__ q, const __bf16* __restrict__ kv,
                       const __bf16* __restrict__ vT, __bf16* __restrict__ ao) {
  __shared__ __align__(16) char ldsQ[8192];
  __shared__ __align__(16) char ldsK[8192];
  __shared__ __align__(16) char ldsV[8192];
  __shared__ __align__(16) char ldsP[4][2048];
  const int tid = threadIdx.x, ln = tid & 63, w = tid >> 6;
  const int qt = blockIdx.x, bh = blockIdx.y;
  const int b = bh / HEADS, h = bh % HEADS;
  const char* qg = (const char*)(q + ((size_t)(b * 2048 + qt * 64)) * 768 + h * 64);
  const char* kg = (const char*)(kv + ((size_t)b * 1024) * 1536 + h * 64);
  const char* vg = (const char*)(vT + ((size_t)(b * 768 + h * 64)) * 1024);

  // stage Q (64x64 bf16), swizzled
#pragma unroll
  for (int c = 0; c < 2; ++c) {
    int off = c * 4096 + tid * 16;
    int row = off >> 7;
    int s = ((off >> 4) & 7) ^ (row & 7);
    gload16(qg + (size_t)row * 1536 + (s << 4), ldsQ + c * 4096 + (w << 10));
  }
  __syncthreads();
  bf16x8 qf[2];
  {
    int row = w * 16 + (ln & 15);
#pragma unroll
    for (int kk = 0; kk < 2; ++kk)
      qf[kk] = *(const bf16x8*)(ldsQ + row * 128 + (((kk * 4 + (ln >> 4)) ^ (row & 7)) << 4));
  }
  f32x4 acc[4] = {};
  float mrow[4] = {-1e30f, -1e30f, -1e30f, -1e30f};
  float lrow[4] = {};
  for (int t = 0; t < 16; ++t) {
    __syncthreads();  // all waves done reading prev K/V
#pragma unroll
    for (int c = 0; c < 2; ++c) {
      int off = c * 4096 + tid * 16;
      int row = off >> 7;
      int s = ((off >> 4) & 7) ^ (row & 7);
      gload16(kg + (size_t)(t * 64 + row) * 3072 + (s << 4), ldsK + c * 4096 + (w << 10));
      gload16(vg + (size_t)row * 2048 + t * 128 + (s << 4), ldsV + c * 4096 + (w << 10));
    }
    __syncthreads();  // drains vmcnt: K/V staged

    // S = Q K^T  (per wave: 16 q rows x 64 kv)
    f32x4 sf[4] = {};
#pragma unroll
    for (int kk = 0; kk < 2; ++kk)
#pragma unroll
      for (int nt = 0; nt < 4; ++nt) {
        int row = nt * 16 + (ln & 15);
        bf16x8 kf = *(const bf16x8*)(ldsK + row * 128 + (((kk * 4 + (ln >> 4)) ^ (row & 7)) << 4));
        sf[nt] = __builtin_amdgcn_mfma_f32_16x16x32_bf16(qf[kk], kf, sf[nt], 0, 0, 0);
      }
    // online softmax; S rows live at (ln>>4)*4+jj, cols at ln&15 (+16*nt)
    float corr[4];
#pragma unroll
    for (int jj = 0; jj < 4; ++jj) {
      float mx = fmaxf(fmaxf(sf[0][jj], sf[1][jj]), fmaxf(sf[2][jj], sf[3][jj])) * SCALE;
#pragma unroll
      for (int o = 1; o <= 8; o <<= 1) mx = fmaxf(mx, __shfl_xor(mx, o, 64));
      float mn = fmaxf(mrow[jj], mx);
      corr[jj] = __expf(mrow[jj] - mn);
      mrow[jj] = mn;
    }
    float psum[4] = {};
    char* pb = ldsP[w];
#pragma unroll
    for (int nt = 0; nt < 4; ++nt)
#pragma unroll
      for (int jj = 0; jj < 4; ++jj) {
        float p = __expf(sf[nt][jj] * SCALE - mrow[jj]);
        psum[jj] += p;
        int prow = ((ln >> 4) << 2) + jj;
        int pc = (nt * 16 + (ln & 15)) * 2;
        *(__bf16*)(pb + prow * 128 + (pc ^ ((prow & 7) << 4))) = (__bf16)p;
      }
#pragma unroll
    for (int jj = 0; jj < 4; ++jj) {
      float sres = psum[jj];
#pragma unroll
      for (int o = 1; o <= 8; o <<= 1) sres += __shfl_xor(sres, o, 64);
      lrow[jj] = lrow[jj] * corr[jj] + sres;
#pragma unroll
      for (int dt = 0; dt < 4; ++dt) acc[dt][jj] *= corr[jj];
    }
    asm volatile("s_waitcnt lgkmcnt(0)" ::: "memory");  // P writes -> P reads
    bf16x8 pf[2];
    {
      int row = ln & 15;
#pragma unroll
      for (int kk = 0; kk < 2; ++kk)
        pf[kk] = *(const bf16x8*)(pb + row * 128 + (((kk * 4 + (ln >> 4)) ^ (row & 7)) << 4));
    }
    // O += P V : B-operand from vT tile [d][m]
#pragma unroll
    for (int kk = 0; kk < 2; ++kk)
#pragma unroll
      for (int dt = 0; dt < 4; ++dt) {
        int row = dt * 16 + (ln & 15);
        bf16x8 vf = *(const bf16x8*)(ldsV + row * 128 + (((kk * 4 + (ln >> 4)) ^ (row & 7)) << 4));
        acc[dt] = __builtin_amdgcn_mfma_f32_16x16x32_bf16(pf[kk], vf, acc[dt], 0, 0, 0);
      }
  }
  size_t orow = (size_t)(b * 2048 + qt * 64 + w * 16 + ((ln >> 4) << 2));
  int oc = h * 64 + (ln & 15);
#pragma unroll
  for (int jj = 0; jj < 4; ++jj) {
    float inv = 1.0f / lrow[jj];
#pragma unroll
    for (int dt = 0; dt < 4; ++dt)
      ao[(orow + jj) * 768 + oc + dt * 16] = (__bf16)(acc[dt][jj] * inv);
  }
}

extern "C" void kernel_launch(void* const* d_in, const int* in_sizes, int n_in,
                              void* d_out, int out_size, void* d_ws, size_t ws_size,
                              hipStream_t stream) {
  const float* x = (const float*)d_in[0];
  const float* r = (const float*)d_in[1];
  const float* Wq = (const float*)d_in[2];
  const float* Wkv = (const float*)d_in[3];
  const float* Wp = (const float*)d_in[4];
  const float* bp = (const float*)d_in[5];

  char* ws = (char*)d_ws;
  __bf16* xb  = (__bf16*)ws; ws += (size_t)6291456 * 2;  // x bf16 (8192x768)
  __bf16* rb  = (__bf16*)ws; ws += (size_t)3145728 * 2;  // r bf16 (4096x768)
  __bf16* wqt = (__bf16*)ws; ws += (size_t)589824 * 2;   // W_q^T (768x768)
  __bf16* wkvt= (__bf16*)ws; ws += (size_t)1179648 * 2;  // W_kv^T (1536x768)
  __bf16* wpt = (__bf16*)ws; ws += (size_t)589824 * 2;   // W_proj^T (768x768)
  __bf16* qb  = (__bf16*)ws; ws += (size_t)6291456 * 2;  // q (8192x768)
  __bf16* kvb = (__bf16*)ws; ws += (size_t)6291456 * 2;  // kv (4096x1536)
  __bf16* vT  = (__bf16*)ws; ws += (size_t)3145728 * 2;  // v^T (4 x 768 x 1024)
  __bf16* ao  = (__bf16*)ws;                              // attn out (8192x768)

  k_cast<<<6144, 256, 0, stream>>>(x, xb, 6291456);
  k_cast<<<3072, 256, 0, stream>>>(r, rb, 3145728);
  k_twc<<<dim3(24, 24), 256, 0, stream>>>(Wq, wqt, 768, 768);
  k_twc<<<dim3(48, 24), 256, 0, stream>>>(Wkv, wkvt, 768, 1536);
  k_twc<<<dim3(24, 24), 256, 0, stream>>>(Wp, wpt, 768, 768);
  k_gemm<true><<<dim3(6, 64), 256, 0, stream>>>(xb, wqt, qb, nullptr, 8192, 768, 768);
  k_gemm<true><<<dim3(12, 32), 256, 0, stream>>>(rb, wkvt, kvb, nullptr, 4096, 1536, 768);
  k_tv<<<dim3(32, 24, 4), 256, 0, stream>>>(kvb, vT);
  k_attn<<<dim3(32, 48), 256, 0, stream>>>(qb, kvb, vT, ao);
  k_gemm<false><<<dim3(6, 64), 256, 0, stream>>>(ao, wpt, d_out, bp, 8192, 768, 768);
}

// Round 2
// 132.809 us; speedup vs baseline: 1.2379x; 1.2379x over previous
//
#include <hip/hip_runtime.h>
#include <hip/hip_bf16.h>
#include <cstdint>

#define HEADS 12

typedef __attribute__((ext_vector_type(8))) __bf16 bf16x8;
typedef __attribute__((ext_vector_type(4))) __bf16 bf16x4;
typedef __attribute__((ext_vector_type(4))) float f32x4;

#define AS1 __attribute__((address_space(1)))
#define AS3 __attribute__((address_space(3)))

__device__ __forceinline__ void gload16(const void* src, void* lds) {
  __builtin_amdgcn_global_load_lds((AS1 void*)src, (AS3 void*)lds, 16, 0, 0);
}

__device__ __forceinline__ uint32_t cvtpk(float lo, float hi) {
  uint32_t r;
  asm("v_cvt_pk_bf16_f32 %0, %1, %2" : "=v"(r) : "v"(lo), "v"(hi));
  return r;
}

// ---------------- cast fp32 -> bf16 (flat, vectorized) ----------------
__global__ void k_cast(const float* __restrict__ in, __bf16* __restrict__ out, int n) {
  int i = (blockIdx.x * 256 + threadIdx.x) * 4;
  if (i + 3 < n) {
    float4 v = *(const float4*)(in + i);
    bf16x4 o;
    o[0] = (__bf16)v.x; o[1] = (__bf16)v.y; o[2] = (__bf16)v.z; o[3] = (__bf16)v.w;
    *(bf16x4*)(out + i) = o;
  }
}

// ------------- transpose+cast weight: W[K][N] f32 -> Wt[N][K] bf16 (×scale) -------------
__global__ void k_twc(const float* __restrict__ W, __bf16* __restrict__ Wt, int K, int N, float scale) {
  __shared__ float tile[32][33];
  int nt = blockIdx.x, kt = blockIdx.y;
  int c = threadIdx.x & 31, r0 = threadIdx.x >> 5;
#pragma unroll
  for (int i = 0; i < 4; ++i) {
    int r = r0 + i * 8;
    tile[r][c] = W[(size_t)(kt * 32 + r) * N + nt * 32 + c];
  }
  __syncthreads();
#pragma unroll
  for (int i = 0; i < 4; ++i) {
    int r = r0 + i * 8;
    Wt[(size_t)(nt * 32 + r) * K + kt * 32 + c] = (__bf16)(tile[c][r] * scale);
  }
}

// ------------- transpose V slice of kv into vT[b][h*64+d][m] (bf16) -------------
__global__ void k_tv(const __bf16* __restrict__ kv, __bf16* __restrict__ vT) {
  __shared__ __bf16 tile[32][33];
  int mt = blockIdx.x, ct = blockIdx.y, b = blockIdx.z;
  int c = threadIdx.x & 31, r0 = threadIdx.x >> 5;
#pragma unroll
  for (int i = 0; i < 4; ++i) {
    int r = r0 + i * 8;  // m-local
    tile[r][c] = kv[((size_t)(b * 1024 + mt * 32 + r)) * 1536 + 768 + ct * 32 + c];
  }
  __syncthreads();
#pragma unroll
  for (int i = 0; i < 4; ++i) {
    int r = r0 + i * 8;  // c-local
    vT[((size_t)(b * 768 + ct * 32 + r)) * 1024 + mt * 32 + c] = tile[c][r];
  }
}

// ---------------- bf16 GEMM: C[M][N] = A[M][K] * Bt[N][K]^T ----------------
template<bool BF16OUT>
__global__ __launch_bounds__(256, 2) void k_gemm(
    const __bf16* __restrict__ A, const __bf16* __restrict__ Bt,
    void* __restrict__ C, const float* __restrict__ bias, int M, int N, int K) {
  __shared__ __align__(16) char ldsA[2][16384];
  __shared__ __align__(16) char ldsB[2][16384];
  const int tid = threadIdx.x;
  const int ln = tid & 63;
  const int w = tid >> 6;
  const int bm0 = blockIdx.y * 128, bn0 = blockIdx.x * 128;
  const int wm0 = (w >> 1) * 64, wn0 = (w & 1) * 64;

  auto stage = [&](char* lds, const __bf16* G, int row0, int k0) {
    const char* gb = (const char*)(G + (size_t)row0 * K + k0);
#pragma unroll
    for (int c = 0; c < 4; ++c) {
      int off = c * 4096 + tid * 16;
      int row = off >> 7;
      int s = ((off >> 4) & 7) ^ (row & 7);
      gload16(gb + (size_t)row * (K * 2) + (s << 4), lds + c * 4096 + (w << 10));
    }
  };

  f32x4 acc[4][4] = {};
  const int NK = K >> 6;
  stage(ldsA[0], A, bm0, 0);
  stage(ldsB[0], Bt, bn0, 0);
  __syncthreads();
  for (int kt = 0; kt < NK; ++kt) {
    const char* bufA = ldsA[kt & 1];
    const char* bufB = ldsB[kt & 1];
    if (kt + 1 < NK) {
      stage(ldsA[(kt + 1) & 1], A, bm0, (kt + 1) << 6);
      stage(ldsB[(kt + 1) & 1], Bt, bn0, (kt + 1) << 6);
    }
    bf16x8 af[2][4], bf[2][4];
#pragma unroll
    for (int kk = 0; kk < 2; ++kk)
#pragma unroll
      for (int mt = 0; mt < 4; ++mt) {
        int row = wm0 + mt * 16 + (ln & 15);
        af[kk][mt] = *(const bf16x8*)(bufA + row * 128 + (((kk * 4 + (ln >> 4)) ^ (row & 7)) << 4));
      }
#pragma unroll
    for (int kk = 0; kk < 2; ++kk)
#pragma unroll
      for (int nt = 0; nt < 4; ++nt) {
        int row = wn0 + nt * 16 + (ln & 15);
        bf[kk][nt] = *(const bf16x8*)(bufB + row * 128 + (((kk * 4 + (ln >> 4)) ^ (row & 7)) << 4));
      }
#pragma unroll
    for (int kk = 0; kk < 2; ++kk)
#pragma unroll
      for (int mt = 0; mt < 4; ++mt)
#pragma unroll
        for (int nt = 0; nt < 4; ++nt)
          acc[mt][nt] = __builtin_amdgcn_mfma_f32_16x16x32_bf16(af[kk][mt], bf[kk][nt], acc[mt][nt], 0, 0, 0);
    __syncthreads();
  }
#pragma unroll
  for (int mt = 0; mt < 4; ++mt) {
    int row = bm0 + wm0 + mt * 16 + ((ln >> 4) << 2);
#pragma unroll
    for (int nt = 0; nt < 4; ++nt) {
      int col = bn0 + wn0 + nt * 16 + (ln & 15);
      if (BF16OUT) {
        __bf16* Cb = (__bf16*)C;
#pragma unroll
        for (int jj = 0; jj < 4; ++jj)
          Cb[(size_t)(row + jj) * N + col] = (__bf16)acc[mt][nt][jj];
      } else {
        float* Cf = (float*)C;
        float bv = bias[col];
#pragma unroll
        for (int jj = 0; jj < 4; ++jj)
          Cf[(size_t)(row + jj) * N + col] = acc[mt][nt][jj] + bv;
      }
    }
  }
}

// ---------------- flash attention, swapped-operand (T12) ----------------
// block = 128 q rows x (b,h). 4 waves, each wave 32 q rows (m=0,1 -> 16 each).
// S^T = mfma(K_frag, Q_frag): lane g=ln>>4 holds P[kv=16nt+4g+jj][q=ln&15].
// P^T redistribution to PV B-frag via cvt_pk_bf16 + permlane32/16_swap.
// O^T = mfma(V^T_frag, P^T_frag). K/V double-buffered, 1 barrier/tile.
__global__ __launch_bounds__(256, 4) void k_attn(
    const __bf16* __restrict__ q, const __bf16* __restrict__ kv,
    const __bf16* __restrict__ vT, __bf16* __restrict__ ao) {
  __shared__ __align__(16) char ldsK[2][8192];
  __shared__ __align__(16) char ldsV[2][8192];
  const int tid = threadIdx.x, ln = tid & 63, w = tid >> 6, g = ln >> 4;
  const int qt = blockIdx.x, bh = blockIdx.y;
  const int b = bh / HEADS, h = bh % HEADS;
  const int qbase = b * 2048 + qt * 128 + w * 32;

  // Q fragments direct to registers: qf[m][kk] = Q[q=qbase+m*16+(ln&15)][d contig]
  bf16x8 qf[2][2];
#pragma unroll
  for (int m = 0; m < 2; ++m)
#pragma unroll
    for (int kk = 0; kk < 2; ++kk)
      qf[m][kk] = *(const bf16x8*)(q + (size_t)(qbase + m * 16 + (ln & 15)) * 768 + h * 64 + (kk * 4 + g) * 8);

  const char* kgb = (const char*)(kv + ((size_t)b * 1024) * 1536 + h * 64);
  const char* vgb = (const char*)(vT + ((size_t)(b * 768 + h * 64)) * 1024);

  auto stageKV = [&](int t, int buf) {
#pragma unroll
    for (int c = 0; c < 2; ++c) {
      int off = c * 4096 + tid * 16;
      int row = off >> 7;
      int s = ((off >> 4) & 7) ^ (row & 7);
      gload16(kgb + (size_t)(t * 64 + row) * 3072 + (s << 4), ldsK[buf] + c * 4096 + w * 1024);
      gload16(vgb + (size_t)row * 2048 + (size_t)t * 128 + (s << 4), ldsV[buf] + c * 4096 + w * 1024);
    }
  };

  f32x4 acc[2][4] = {};
  float mrow[2] = {-1e30f, -1e30f};
  float lrow[2] = {0.f, 0.f};

  stageKV(0, 0);
  asm volatile("s_waitcnt vmcnt(0)" ::: "memory");
  __builtin_amdgcn_s_barrier();

  for (int t = 0; t < 16; ++t) {
    if (t < 15) stageKV(t + 1, (t + 1) & 1);
    const char* bufK = ldsK[t & 1];
    const char* bufV = ldsV[t & 1];

    // S^T = K . Q^T  (A = K-frag, B = Q-frag)
    f32x4 sf[2][4] = {};
#pragma unroll
    for (int kk = 0; kk < 2; ++kk)
#pragma unroll
      for (int nt = 0; nt < 4; ++nt) {
        int row = nt * 16 + (ln & 15);
        bf16x8 kf = *(const bf16x8*)(bufK + row * 128 + (((kk * 4 + g) ^ (row & 7)) << 4));
        sf[0][nt] = __builtin_amdgcn_mfma_f32_16x16x32_bf16(kf, qf[0][kk], sf[0][nt], 0, 0, 0);
        sf[1][nt] = __builtin_amdgcn_mfma_f32_16x16x32_bf16(kf, qf[1][kk], sf[1][nt], 0, 0, 0);
      }

    // online softmax per m (lane owns q = qbase + m*16 + (ln&15); kv slice 16nt+4g+jj)
    bf16x8 pb[2][2];
#pragma unroll
    for (int m = 0; m < 2; ++m) {
      f32x4 v01 = sf[m][0], v1 = sf[m][1], v2 = sf[m][2], v3 = sf[m][3];
      f32x4 mv;
#pragma unroll
      for (int jj = 0; jj < 4; ++jj)
        mv[jj] = fmaxf(fmaxf(v01[jj], v1[jj]), fmaxf(v2[jj], v3[jj]));
      float mx = fmaxf(fmaxf(mv[0], mv[1]), fmaxf(mv[2], mv[3]));
      mx = fmaxf(mx, __shfl_xor(mx, 16, 64));
      mx = fmaxf(mx, __shfl_xor(mx, 32, 64));
      float mn = fmaxf(mrow[m], mx);
      float corr = __expf(mrow[m] - mn);
      mrow[m] = mn;
      float p[4][4];
      f32x4 ps = {0.f, 0.f, 0.f, 0.f};
#pragma unroll
      for (int nt = 0; nt < 4; ++nt)
#pragma unroll
        for (int jj = 0; jj < 4; ++jj) {
          float e = __expf(sf[m][nt][jj] - mn);
          p[nt][jj] = e;
          ps[jj] += e;
        }
      float sm = (ps[0] + ps[1]) + (ps[2] + ps[3]);
      sm += __shfl_xor(sm, 16, 64);
      sm += __shfl_xor(sm, 32, 64);
      lrow[m] = lrow[m] * corr + sm;
#pragma unroll
      for (int dt = 0; dt < 4; ++dt) acc[m][dt] *= corr;

      // pack to bf16 pairs, then exchange across lane groups:
      // pb[kk][e] = P[kv=32kk+8g+e][q]; source group 2(g&1)+(e>>2), nt=2kk+(g>>1)
      uint32_t c0[4], c1[4];
#pragma unroll
      for (int nt = 0; nt < 4; ++nt) {
        c0[nt] = cvtpk(p[nt][0], p[nt][1]);
        c1[nt] = cvtpk(p[nt][2], p[nt][3]);
      }
#pragma unroll
      for (int kk = 0; kk < 2; ++kk) {
        uint32_t x0 = c0[2 * kk], y0 = c0[2 * kk + 1];
        asm("v_permlane32_swap_b32 %0, %1" : "+v"(x0), "+v"(y0));
        asm("v_permlane16_swap_b32 %0, %1" : "+v"(x0), "+v"(y0));
        uint32_t x1 = c1[2 * kk], y1 = c1[2 * kk + 1];
        asm("v_permlane32_swap_b32 %0, %1" : "+v"(x1), "+v"(y1));
        asm("v_permlane16_swap_b32 %0, %1" : "+v"(x1), "+v"(y1));
        union { uint32_t u[4]; bf16x8 v; } pk;
        pk.u[0] = x0; pk.u[1] = x1; pk.u[2] = y0; pk.u[3] = y1;
        pb[m][kk] = pk.v;
      }
    }

    // O^T += V^T . P^T  (A = V^T-frag, B = P^T-frag)
#pragma unroll
    for (int kk = 0; kk < 2; ++kk)
#pragma unroll
      for (int dt = 0; dt < 4; ++dt) {
        int row = dt * 16 + (ln & 15);
        bf16x8 vf = *(const bf16x8*)(bufV + row * 128 + (((kk * 4 + g) ^ (row & 7)) << 4));
        acc[0][dt] = __builtin_amdgcn_mfma_f32_16x16x32_bf16(vf, pb[0][kk], acc[0][dt], 0, 0, 0);
        acc[1][dt] = __builtin_amdgcn_mfma_f32_16x16x32_bf16(vf, pb[1][kk], acc[1][dt], 0, 0, 0);
      }

    asm volatile("s_waitcnt vmcnt(0)" ::: "memory");
    __builtin_amdgcn_s_barrier();
  }

  // epilogue: acc[m][dt][jj] = O^T[d=16dt+4g+jj][q=qbase+m*16+(ln&15)]
#pragma unroll
  for (int m = 0; m < 2; ++m) {
    float inv = 1.0f / lrow[m];
    size_t rowb = (size_t)(qbase + m * 16 + (ln & 15)) * 768 + h * 64;
#pragma unroll
    for (int dt = 0; dt < 4; ++dt) {
      bf16x4 o;
#pragma unroll
      for (int jj = 0; jj < 4; ++jj) o[jj] = (__bf16)(acc[m][dt][jj] * inv);
      *(bf16x4*)(ao + rowb + 16 * dt + 4 * g) = o;
    }
  }
}

extern "C" void kernel_launch(void* const* d_in, const int* in_sizes, int n_in,
                              void* d_out, int out_size, void* d_ws, size_t ws_size,
                              hipStream_t stream) {
  const float* x = (const float*)d_in[0];
  const float* r = (const float*)d_in[1];
  const float* Wq = (const float*)d_in[2];
  const float* Wkv = (const float*)d_in[3];
  const float* Wp = (const float*)d_in[4];
  const float* bp = (const float*)d_in[5];

  char* ws = (char*)d_ws;
  __bf16* xb  = (__bf16*)ws; ws += (size_t)6291456 * 2;  // x bf16 (8192x768)
  __bf16* rb  = (__bf16*)ws; ws += (size_t)3145728 * 2;  // r bf16 (4096x768)
  __bf16* wqt = (__bf16*)ws; ws += (size_t)589824 * 2;   // W_q^T * SCALE (768x768)
  __bf16* wkvt= (__bf16*)ws; ws += (size_t)1179648 * 2;  // W_kv^T (1536x768)
  __bf16* wpt = (__bf16*)ws; ws += (size_t)589824 * 2;   // W_proj^T (768x768)
  __bf16* qb  = (__bf16*)ws; ws += (size_t)6291456 * 2;  // q (8192x768), pre-scaled
  __bf16* kvb = (__bf16*)ws; ws += (size_t)6291456 * 2;  // kv (4096x1536)
  __bf16* vT  = (__bf16*)ws; ws += (size_t)3145728 * 2;  // v^T (4 x 768 x 1024)
  __bf16* ao  = (__bf16*)ws;                              // attn out (8192x768)

  k_cast<<<6144, 256, 0, stream>>>(x, xb, 6291456);
  k_cast<<<3072, 256, 0, stream>>>(r, rb, 3145728);
  k_twc<<<dim3(24, 24), 256, 0, stream>>>(Wq, wqt, 768, 768, 0.125f);
  k_twc<<<dim3(48, 24), 256, 0, stream>>>(Wkv, wkvt, 768, 1536, 1.0f);
  k_twc<<<dim3(24, 24), 256, 0, stream>>>(Wp, wpt, 768, 768, 1.0f);
  k_gemm<true><<<dim3(6, 64), 256, 0, stream>>>(xb, wqt, qb, nullptr, 8192, 768, 768);
  k_gemm<true><<<dim3(12, 32), 256, 0, stream>>>(rb, wkvt, kvb, nullptr, 4096, 1536, 768);
  k_tv<<<dim3(32, 24, 4), 256, 0, stream>>>(kvb, vT);
  k_attn<<<dim3(16, 48), 256, 0, stream>>>(qb, kvb, vT, ao);
  k_gemm<false><<<dim3(6, 64), 256, 0, stream>>>(ao, wpt, d_out, bp, 8192, 768, 768);
}